// Round 11
// baseline (1220.028 us; speedup 1.0000x reference)
//
#include <hip/hip_runtime.h>
#include <hip/hip_bf16.h>
#include <cstdint>
#include <cstddef>

#define Bsz  256
#define Tn   4096
#define In   8
#define Hn   32
#define TGTn 8

// sigmoid(p) = 1/(1+exp2(ALPHA*p)) with ALPHA = -log2(e)
// tanh path:  exp(2y) = exp2(BETA*y)  with BETA  = 2*log2(e)
#define ALPHA (-1.44269504088896341f)
#define BETA  ( 2.88539008177792682f)

#if __has_builtin(__builtin_amdgcn_exp2f)
__device__ __forceinline__ float exp2f_fast(float x) { return __builtin_amdgcn_exp2f(x); }
#else
__device__ __forceinline__ float exp2f_fast(float x) { return __expf(x * 0.69314718056f); }
#endif
__device__ __forceinline__ float rcpf(float x) { return __builtin_amdgcn_rcpf(x); }

// DPP rotate within 16-lane rows; direction convention handled by probing.
template<int N>
__device__ __forceinline__ float dpp_ror(float x) {
    int xi = __float_as_int(x);
    int r = __builtin_amdgcn_update_dpp(xi, xi, 0x120 + N, 0xF, 0xF, false);
    return __int_as_float(r);
}

// x_l + x_{l^32} in every lane (hazards handled by compiler builtin).
__device__ __forceinline__ float half_sum(float x) {
    auto r = __builtin_amdgcn_permlane32_swap(__float_as_int(x), __float_as_int(x),
                                              false, false);
    return __int_as_float((int)r[0]) + __int_as_float((int)r[1]);
}

// Unordered pair {f(lane&15), f(16+(lane&15))}; caller probes slot order.
__device__ __forceinline__ void row16_pair(float x, float& a_out, float& b_out) {
    auto r = __builtin_amdgcn_permlane16_swap(__float_as_int(x), __float_as_int(x),
                                              false, false);
    a_out = __int_as_float((int)r[0]);
    b_out = __int_as_float((int)r[1]);
}

// Probe butterfly (cold): must match BCAST's H0..H15 construction exactly.
__device__ __forceinline__ void gather16_probe(float v, float H[16]) {
    H[0]  = v;
    H[1]  = dpp_ror<1>(H[0]);
    H[2]  = dpp_ror<2>(H[0]);  H[3]  = dpp_ror<2>(H[1]);
    H[4]  = dpp_ror<4>(H[0]);  H[5]  = dpp_ror<4>(H[1]);
    H[6]  = dpp_ror<4>(H[2]);  H[7]  = dpp_ror<4>(H[3]);
    H[8]  = dpp_ror<8>(H[0]);  H[9]  = dpp_ror<8>(H[1]);
    H[10] = dpp_ror<8>(H[2]);  H[11] = dpp_ror<8>(H[3]);
    H[12] = dpp_ror<8>(H[4]);  H[13] = dpp_ror<8>(H[5]);
    H[14] = dpp_ror<8>(H[6]);  H[15] = dpp_ror<8>(H[7]);
}

// W = w_ih @ E : [96,8]
__global__ void fuse_wih_kernel(const float* __restrict__ w_ih,
                                const float* __restrict__ E,
                                float* __restrict__ Wf) {
    int tid = threadIdx.x;                // 768 threads
    int g = tid >> 3, i = tid & 7;
    float acc = 0.f;
#pragma unroll
    for (int k = 0; k < Hn; ++k)
        acc = fmaf(w_ih[g * Hn + k], E[k * In + i], acc);
    Wf[g * In + i] = acc;
}

// gx[b][trel][gate][j], PRE-SCALED: r,z by 0.5*ALPHA (halved: both wave-halves
// add it, half_sum doubles it back); n by BETA (not halved: added after the
// half-sum). Biases folded (b_hh_n stays in the gru chain init).
__global__ void gx_kernel(const float* __restrict__ x,
                          const float* __restrict__ Wf,
                          const float* __restrict__ b_ih,
                          const float* __restrict__ b_hh,
                          float* __restrict__ gx,
                          int t0, int Tc) {
    int local = blockIdx.x * 256 + threadIdx.x;   // over Tc*32
    int b     = blockIdx.y;
    int j     = local & 31;
    int trel  = local >> 5;
    const float* xr = x + ((size_t)b * Tn + t0 + trel) * In;
    float x0 = xr[0], x1 = xr[1], x2 = xr[2], x3 = xr[3],
          x4 = xr[4], x5 = xr[5], x6 = xr[6], x7 = xr[7];
    const float* wr = &Wf[(0 * Hn + j) * In];
    const float* wz = &Wf[(1 * Hn + j) * In];
    const float* wn = &Wf[(2 * Hn + j) * In];
    float ar = b_ih[j] + b_hh[j];
    float az = b_ih[Hn + j] + b_hh[Hn + j];
    float an = b_ih[2 * Hn + j];
    ar = fmaf(wr[0],x0,ar); ar = fmaf(wr[1],x1,ar); ar = fmaf(wr[2],x2,ar); ar = fmaf(wr[3],x3,ar);
    ar = fmaf(wr[4],x4,ar); ar = fmaf(wr[5],x5,ar); ar = fmaf(wr[6],x6,ar); ar = fmaf(wr[7],x7,ar);
    az = fmaf(wz[0],x0,az); az = fmaf(wz[1],x1,az); az = fmaf(wz[2],x2,az); az = fmaf(wz[3],x3,az);
    az = fmaf(wz[4],x4,az); az = fmaf(wz[5],x5,az); az = fmaf(wz[6],x6,az); az = fmaf(wz[7],x7,az);
    an = fmaf(wn[0],x0,an); an = fmaf(wn[1],x1,an); an = fmaf(wn[2],x2,an); an = fmaf(wn[3],x3,an);
    an = fmaf(wn[4],x4,an); an = fmaf(wn[5],x5,an); an = fmaf(wn[6],x6,an); an = fmaf(wn[7],x7,an);
    float* o = gx + ((size_t)(b * Tc + trel) * 3) * Hn + j;
    o[0]      = 0.5f * ALPHA * ar;
    o[Hn]     = 0.5f * ALPHA * az;
    o[2 * Hn] = BETA * an;
}

// Rebuild H0..H15 (all 16 h of this lane's K-half, probed order) from hj.
#define BCAST()                                                                      \
  {                                                                                  \
    float va, vb;                                                                    \
    row16_pair(hj, va, vb);                                                          \
    float gv = pick_a ? va : vb;          /* = h[grp*16 + (lane&15)] */              \
    H0  = gv;                                                                        \
    H1  = dpp_ror<1>(H0);                                                            \
    H2  = dpp_ror<2>(H0);  H3  = dpp_ror<2>(H1);                                     \
    H4  = dpp_ror<4>(H0);  H5  = dpp_ror<4>(H1);                                     \
    H6  = dpp_ror<4>(H2);  H7  = dpp_ror<4>(H3);                                     \
    H8  = dpp_ror<8>(H0);  H9  = dpp_ror<8>(H1);                                     \
    H10 = dpp_ror<8>(H2);  H11 = dpp_ror<8>(H3);                                     \
    H12 = dpp_ror<8>(H4);  H13 = dpp_ror<8>(H5);                                     \
    H14 = dpp_ror<8>(H6);  H15 = dpp_ror<8>(H7);                                     \
  }

// One GRU step: consume slot (GA,GB,GC), refill it with step s+4's values.
// Scalar fma chains, inits = pre-scaled gx / half-bias (no post-adds).
#define GRU_STEP(GA, GB, GC)                                                         \
  {                                                                                  \
    float ar = GA, az = GB, an = bhn_h;                                              \
    ar = fmaf(H0,  wr0,  ar);  az = fmaf(H0,  wz0,  az);  an = fmaf(H0,  wn0,  an);  \
    ar = fmaf(H1,  wr1,  ar);  az = fmaf(H1,  wz1,  az);  an = fmaf(H1,  wn1,  an);  \
    ar = fmaf(H2,  wr2,  ar);  az = fmaf(H2,  wz2,  az);  an = fmaf(H2,  wn2,  an);  \
    ar = fmaf(H3,  wr3,  ar);  az = fmaf(H3,  wz3,  az);  an = fmaf(H3,  wn3,  an);  \
    ar = fmaf(H4,  wr4,  ar);  az = fmaf(H4,  wz4,  az);  an = fmaf(H4,  wn4,  an);  \
    ar = fmaf(H5,  wr5,  ar);  az = fmaf(H5,  wz5,  az);  an = fmaf(H5,  wn5,  an);  \
    ar = fmaf(H6,  wr6,  ar);  az = fmaf(H6,  wz6,  az);  an = fmaf(H6,  wn6,  an);  \
    ar = fmaf(H7,  wr7,  ar);  az = fmaf(H7,  wz7,  az);  an = fmaf(H7,  wn7,  an);  \
    ar = fmaf(H8,  wr8,  ar);  az = fmaf(H8,  wz8,  az);  an = fmaf(H8,  wn8,  an);  \
    ar = fmaf(H9,  wr9,  ar);  az = fmaf(H9,  wz9,  az);  an = fmaf(H9,  wn9,  an);  \
    ar = fmaf(H10, wr10, ar);  az = fmaf(H10, wz10, az);  an = fmaf(H10, wn10, an);  \
    ar = fmaf(H11, wr11, ar);  az = fmaf(H11, wz11, az);  an = fmaf(H11, wn11, an);  \
    ar = fmaf(H12, wr12, ar);  az = fmaf(H12, wz12, az);  an = fmaf(H12, wn12, an);  \
    ar = fmaf(H13, wr13, ar);  az = fmaf(H13, wz13, az);  an = fmaf(H13, wn13, an);  \
    ar = fmaf(H14, wr14, ar);  az = fmaf(H14, wz14, az);  an = fmaf(H14, wn14, an);  \
    ar = fmaf(H15, wr15, ar);  az = fmaf(H15, wz15, az);  an = fmaf(H15, wn15, an);  \
    float cr  = half_sum(ar);             /* = ALPHA*(hdot+xdot+bias) */             \
    float cz  = half_sum(az);                                                        \
    float chn = half_sum(an);             /* = BETA*(hdot+b_hh_n)    */              \
    float r = rcpf(1.f + exp2f_fast(cr));                                            \
    float z = rcpf(1.f + exp2f_fast(cz));                                            \
    float e = exp2f_fast(__builtin_fmaf(r, chn, GC));                                \
    float u = rcpf(e + 1.f);                                                         \
    float n = __builtin_fmaf(-2.f, u, 1.f);                                          \
    hj = __builtin_fmaf(z, hj - n, n);                                               \
    BCAST()                                                                          \
    latp_u[j] = hj;                                                                  \
    latp_u += Hn;                        /* uniform -> SALU */                       \
    GA = refp_u[j]; GB = refp_u[j + Hn]; GC = refp_u[j + 2 * Hn];                    \
    refp_u += 3 * Hn;                    /* uniform -> SALU */                       \
  }

#define KEEP(v) asm volatile("" : "+v"(v))
__attribute__((amdgpu_flat_work_group_size(64, 64), amdgpu_waves_per_eu(1, 1)))
__global__ void gru_kernel(const float* __restrict__ gx,    // [B,Tc,3,32] scaled
                           const float* __restrict__ w_hh,  // [96,32]
                           const float* __restrict__ b_hh,  // [96]
                           float* __restrict__ hbuf,        // [B,32] carry
                           float* __restrict__ latents,     // [B,T,32]
                           int t0, int Tc, int first) {
    const int lane = threadIdx.x & 63;
    const int grp  = lane >> 5;     // K-half this lane accumulates
    const int j    = lane & 31;     // hidden row this lane produces
    const int r16  = lane & 15;
    const int b    = blockIdx.x;

    // ---- probe hardware permutation conventions (cold) ----
    int sidx[16];
    {
        float P[16];
        gather16_probe((float)r16, P);
#pragma unroll
        for (int m = 0; m < 16; ++m) sidx[m] = (int)P[m];
    }
    bool pick_a;
    {
        float va, vb;
        row16_pair((float)j, va, vb);
        pick_a = ((int)va == grp * 16 + r16);
    }

    // ---- recurrent weights, probed order, pre-scaled (ALPHA / BETA) ----
    float wr0,wr1,wr2,wr3,wr4,wr5,wr6,wr7,wr8,wr9,wr10,wr11,wr12,wr13,wr14,wr15;
    float wz0,wz1,wz2,wz3,wz4,wz5,wz6,wz7,wz8,wz9,wz10,wz11,wz12,wz13,wz14,wz15;
    float wn0,wn1,wn2,wn3,wn4,wn5,wn6,wn7,wn8,wn9,wn10,wn11,wn12,wn13,wn14,wn15;
#define LOADW(M)                                                                  \
    {                                                                             \
        const int c = grp * 16 + sidx[M];                                         \
        wr##M = ALPHA * w_hh[(0*Hn + j)*Hn + c];                                  \
        wz##M = ALPHA * w_hh[(1*Hn + j)*Hn + c];                                  \
        wn##M = BETA  * w_hh[(2*Hn + j)*Hn + c];                                  \
        KEEP(wr##M); KEEP(wz##M); KEEP(wn##M);                                    \
    }
    LOADW(0) LOADW(1) LOADW(2)  LOADW(3)  LOADW(4)  LOADW(5)  LOADW(6)  LOADW(7)
    LOADW(8) LOADW(9) LOADW(10) LOADW(11) LOADW(12) LOADW(13) LOADW(14) LOADW(15)
#undef LOADW

    float bhn_h = 0.5f * BETA * b_hh[2 * Hn + j];   // halved: both halves add it
    KEEP(bhn_h);

    float* latp_u       = latents + ((size_t)b * Tn + t0) * Hn;  // uniform base
    const float* refp_u = gx + (size_t)b * Tc * 3 * Hn;          // uniform base

    float hj = first ? 0.f : hbuf[b * Hn + j];
    float H0,H1,H2,H3,H4,H5,H6,H7,H8,H9,H10,H11,H12,H13,H14,H15;
    BCAST()

    // ---- 4-deep prefetch ring in named scalars ----
    float g0a = refp_u[j], g0b = refp_u[j+Hn], g0c = refp_u[j+2*Hn]; refp_u += 3*Hn;
    float g1a = refp_u[j], g1b = refp_u[j+Hn], g1c = refp_u[j+2*Hn]; refp_u += 3*Hn;
    float g2a = refp_u[j], g2b = refp_u[j+Hn], g2c = refp_u[j+2*Hn]; refp_u += 3*Hn;
    float g3a = refp_u[j], g3b = refp_u[j+Hn], g3c = refp_u[j+2*Hn]; refp_u += 3*Hn;

#pragma unroll 1
    for (int it = 0; it < Tc / 4; ++it) {
        GRU_STEP(g0a, g0b, g0c)
        GRU_STEP(g1a, g1b, g1c)
        GRU_STEP(g2a, g2b, g2c)
        GRU_STEP(g3a, g3b, g3c)
    }

    if (grp == 0) hbuf[b * Hn + j] = hj;   // carry h to next chunk
}
#undef KEEP

// outputs[b,t,o] = sum_h latents[b,t,h] * E[h,o]
__global__ void decode_kernel(const float* __restrict__ lat,
                              const float* __restrict__ E,
                              float* __restrict__ out) {
    __shared__ float ldsE[Hn * TGTn];
    int tid = threadIdx.x;
    if (tid < Hn * TGTn) ldsE[tid] = E[tid];
    __syncthreads();
    size_t idx = (size_t)blockIdx.x * 256 + tid;   // over B*T*8
    int o      = (int)(idx & (TGTn - 1));
    size_t row = idx >> 3;
    const float* lrow = lat + row * Hn;
    float acc = 0.f;
#pragma unroll
    for (int h = 0; h < Hn; ++h)
        acc = fmaf(lrow[h], ldsE[h * TGTn + o], acc);
    out[idx] = acc;
}

extern "C" void kernel_launch(void* const* d_in, const int* in_sizes, int n_in,
                              void* d_out, int out_size, void* d_ws, size_t ws_size,
                              hipStream_t stream) {
    const float* x    = (const float*)d_in[0];
    const float* E    = (const float*)d_in[1];
    const float* w_ih = (const float*)d_in[2];
    const float* w_hh = (const float*)d_in[3];
    const float* b_ih = (const float*)d_in[4];
    const float* b_hh = (const float*)d_in[5];

    float* out  = (float*)d_out;                         // [B,T,8]
    float* lat  = out + (size_t)Bsz * Tn * TGTn;         // [B,T,32]
    float* Wf   = (float*)d_ws;                          // [96,8]
    float* hbuf = Wf + 1024;                             // [256,32]
    float* gx   = hbuf + Bsz * Hn;                       // chunk buffer

    // largest T-chunk whose gx buffer (+4-step pad) fits the workspace;
    // <=1024 keeps each ~100MB chunk L3-resident between gx and gru.
    size_t avail = (ws_size / 4 > (size_t)(1024 + Bsz * Hn))
                 ? ws_size / 4 - (1024 + Bsz * Hn) : 0;
    int Tc = 1024;
    while (Tc > 8 && (size_t)Bsz * Tc * 3 * Hn + 4 * 3 * Hn > avail) Tc >>= 1;

    fuse_wih_kernel<<<1, 768, 0, stream>>>(w_ih, E, Wf);
    for (int t0 = 0; t0 < Tn; t0 += Tc) {
        gx_kernel<<<dim3(Tc * Hn / 256, Bsz), 256, 0, stream>>>(
            x, Wf, b_ih, b_hh, gx, t0, Tc);
        gru_kernel<<<Bsz, 64, 0, stream>>>(
            gx, w_hh, b_hh, hbuf, lat, t0, Tc, t0 == 0 ? 1 : 0);
    }
    decode_kernel<<<(Bsz * Tn * TGTn) / 256, 256, 0, stream>>>(lat, E, out);
}

// Round 14
// 1143.467 us; speedup vs baseline: 1.0670x; 1.0670x over previous
//
#include <hip/hip_runtime.h>
#include <hip/hip_bf16.h>
#include <cstdint>
#include <cstddef>

#define Bsz  256
#define Tn   4096
#define In   8
#define Hn   32
#define TGTn 8

// sigmoid(p) = 1/(1+exp2(ALPHA*p)) with ALPHA = -log2(e)
// tanh path:  exp(2y) = exp2(BETA*y)  with BETA  = 2*log2(e)
#define ALPHA (-1.44269504088896341f)
#define BETA  ( 2.88539008177792682f)

#if __has_builtin(__builtin_amdgcn_exp2f)
__device__ __forceinline__ float exp2f_fast(float x) { return __builtin_amdgcn_exp2f(x); }
#else
__device__ __forceinline__ float exp2f_fast(float x) { return __expf(x * 0.69314718056f); }
#endif
__device__ __forceinline__ float rcpf(float x) { return __builtin_amdgcn_rcpf(x); }

// x_l + x_{l^32} in every lane (compiler-managed hazards).
__device__ __forceinline__ float half_sum(float x) {
    auto r = __builtin_amdgcn_permlane32_swap(__float_as_int(x), __float_as_int(x),
                                              false, false);
    return __int_as_float((int)r[0]) + __int_as_float((int)r[1]);
}

// W = w_ih @ E : [96,8] (raw; scaling applied at gru init)
__global__ void fuse_wih_kernel(const float* __restrict__ w_ih,
                                const float* __restrict__ E,
                                float* __restrict__ Wf) {
    int tid = threadIdx.x;                // 768 threads
    int g = tid >> 3, i = tid & 7;
    float acc = 0.f;
#pragma unroll
    for (int k = 0; k < Hn; ++k)
        acc = fmaf(w_ih[g * Hn + k], E[k * In + i], acc);
    Wf[g * In + i] = acc;
}

// One GRU step. XA/XB = x[s] (8 floats, uniform); XRA/XRB = ring slot freed
// this step (refilled with x[s+4]). H0..H15 = h of this lane's K-half
// (natural order, from LDS). No barriers: single wave, in-order DS pipe.
#define GRU_STEP(XA, XB, XRA, XRB, DO_REFILL)                                        \
  {                                                                                  \
    /* x-dots: full 8 per lane (r/z weights pre-halved; half_sum doubles) */         \
    float ar = br_h, az = bz_h, anx = bxn_f, anh = bhn_h;                            \
    ar  = fmaf(XA.x, wxr0, ar);  ar  = fmaf(XA.y, wxr1, ar);                         \
    ar  = fmaf(XA.z, wxr2, ar);  ar  = fmaf(XA.w, wxr3, ar);                         \
    ar  = fmaf(XB.x, wxr4, ar);  ar  = fmaf(XB.y, wxr5, ar);                         \
    ar  = fmaf(XB.z, wxr6, ar);  ar  = fmaf(XB.w, wxr7, ar);                         \
    az  = fmaf(XA.x, wxz0, az);  az  = fmaf(XA.y, wxz1, az);                         \
    az  = fmaf(XA.z, wxz2, az);  az  = fmaf(XA.w, wxz3, az);                         \
    az  = fmaf(XB.x, wxz4, az);  az  = fmaf(XB.y, wxz5, az);                         \
    az  = fmaf(XB.z, wxz6, az);  az  = fmaf(XB.w, wxz7, az);                         \
    anx = fmaf(XA.x, wxn0, anx); anx = fmaf(XA.y, wxn1, anx);                        \
    anx = fmaf(XA.z, wxn2, anx); anx = fmaf(XA.w, wxn3, anx);                        \
    anx = fmaf(XB.x, wxn4, anx); anx = fmaf(XB.y, wxn5, anx);                        \
    anx = fmaf(XB.z, wxn6, anx); anx = fmaf(XB.w, wxn7, anx);                        \
    /* h-dots: K-split 16 per gate */                                                \
    ar = fmaf(H0,  wr0,  ar);  az = fmaf(H0,  wz0,  az);  anh = fmaf(H0,  wn0,  anh);\
    ar = fmaf(H1,  wr1,  ar);  az = fmaf(H1,  wz1,  az);  anh = fmaf(H1,  wn1,  anh);\
    ar = fmaf(H2,  wr2,  ar);  az = fmaf(H2,  wz2,  az);  anh = fmaf(H2,  wn2,  anh);\
    ar = fmaf(H3,  wr3,  ar);  az = fmaf(H3,  wz3,  az);  anh = fmaf(H3,  wn3,  anh);\
    ar = fmaf(H4,  wr4,  ar);  az = fmaf(H4,  wz4,  az);  anh = fmaf(H4,  wn4,  anh);\
    ar = fmaf(H5,  wr5,  ar);  az = fmaf(H5,  wz5,  az);  anh = fmaf(H5,  wn5,  anh);\
    ar = fmaf(H6,  wr6,  ar);  az = fmaf(H6,  wz6,  az);  anh = fmaf(H6,  wn6,  anh);\
    ar = fmaf(H7,  wr7,  ar);  az = fmaf(H7,  wz7,  az);  anh = fmaf(H7,  wn7,  anh);\
    ar = fmaf(H8,  wr8,  ar);  az = fmaf(H8,  wz8,  az);  anh = fmaf(H8,  wn8,  anh);\
    ar = fmaf(H9,  wr9,  ar);  az = fmaf(H9,  wz9,  az);  anh = fmaf(H9,  wn9,  anh);\
    ar = fmaf(H10, wr10, ar);  az = fmaf(H10, wz10, az);  anh = fmaf(H10, wn10, anh);\
    ar = fmaf(H11, wr11, ar);  az = fmaf(H11, wz11, az);  anh = fmaf(H11, wn11, anh);\
    ar = fmaf(H12, wr12, ar);  az = fmaf(H12, wz12, az);  anh = fmaf(H12, wn12, anh);\
    ar = fmaf(H13, wr13, ar);  az = fmaf(H13, wz13, az);  anh = fmaf(H13, wn13, anh);\
    ar = fmaf(H14, wr14, ar);  az = fmaf(H14, wz14, az);  anh = fmaf(H14, wn14, anh);\
    ar = fmaf(H15, wr15, ar);  az = fmaf(H15, wz15, az);  anh = fmaf(H15, wn15, anh);\
    float cr  = half_sum(ar);             /* ALPHA*(xdot+hdot+bias)  */              \
    float cz  = half_sum(az);                                                        \
    float chn = half_sum(anh);            /* BETA*(hdot+b_hn)        */              \
    float r = rcpf(1.f + exp2f_fast(cr));                                            \
    float z = rcpf(1.f + exp2f_fast(cz));                                            \
    float e = exp2f_fast(__builtin_fmaf(r, chn, anx));                               \
    float u = rcpf(e + 1.f);                                                         \
    float n = __builtin_fmaf(-2.f, u, 1.f);                                          \
    hj = __builtin_fmaf(z, hj - n, n);                                               \
    lds_h[j] = hj;                        /* in-order DS: no barrier needed */       \
    latb_u[j] = hj;                                                                  \
    latb_u += Hn;                         /* uniform -> SALU */                      \
    if (DO_REFILL) {                                                                 \
        XRA = *(const float4*)refp;                                                  \
        XRB = *(const float4*)(refp + 4);                                            \
        refp += In;                       /* uniform -> SALU */                      \
    }                                                                                \
    /* read back h for next step (latency hidden by next step's x-dots) */           \
    {                                                                                \
        float4 q0 = *(const float4*)&lds_h[grp * 16 + 0];                            \
        float4 q1 = *(const float4*)&lds_h[grp * 16 + 4];                            \
        float4 q2 = *(const float4*)&lds_h[grp * 16 + 8];                            \
        float4 q3 = *(const float4*)&lds_h[grp * 16 + 12];                           \
        H0  = q0.x; H1  = q0.y; H2  = q0.z; H3  = q0.w;                              \
        H4  = q1.x; H5  = q1.y; H6  = q1.z; H7  = q1.w;                              \
        H8  = q2.x; H9  = q2.y; H10 = q2.z; H11 = q2.w;                              \
        H12 = q3.x; H13 = q3.y; H14 = q3.z; H15 = q3.w;                              \
    }                                                                                \
  }

#define KEEP(v) asm volatile("" : "+v"(v))
__attribute__((amdgpu_flat_work_group_size(64, 64), amdgpu_waves_per_eu(1, 1)))
__global__ void gru_kernel(const float* __restrict__ x,     // [B,T,8]
                           const float* __restrict__ Wf,    // [96,8] raw w_ih@E
                           const float* __restrict__ w_hh,  // [96,32]
                           const float* __restrict__ b_ih,  // [96]
                           const float* __restrict__ b_hh,  // [96]
                           float* __restrict__ latents) {   // [B,T,32]
    __shared__ __align__(16) float lds_h[Hn];

    const int lane = threadIdx.x & 63;
    const int grp  = lane >> 5;     // K-half this lane accumulates
    const int j    = lane & 31;     // hidden row this lane produces
    const int b    = blockIdx.x;

    // ---- recurrent weights, NATURAL order (LDS broadcast restores order),
    //      pre-scaled by ALPHA (r,z) / BETA (n) ----
    float wr0,wr1,wr2,wr3,wr4,wr5,wr6,wr7,wr8,wr9,wr10,wr11,wr12,wr13,wr14,wr15;
    float wz0,wz1,wz2,wz3,wz4,wz5,wz6,wz7,wz8,wz9,wz10,wz11,wz12,wz13,wz14,wz15;
    float wn0,wn1,wn2,wn3,wn4,wn5,wn6,wn7,wn8,wn9,wn10,wn11,wn12,wn13,wn14,wn15;
#define LOADW(M)                                                                  \
    {                                                                             \
        const int c = grp * 16 + M;                                               \
        wr##M = ALPHA * w_hh[(0*Hn + j)*Hn + c];                                  \
        wz##M = ALPHA * w_hh[(1*Hn + j)*Hn + c];                                  \
        wn##M = BETA  * w_hh[(2*Hn + j)*Hn + c];                                  \
        KEEP(wr##M); KEEP(wz##M); KEEP(wn##M);                                    \
    }
    LOADW(0) LOADW(1) LOADW(2)  LOADW(3)  LOADW(4)  LOADW(5)  LOADW(6)  LOADW(7)
    LOADW(8) LOADW(9) LOADW(10) LOADW(11) LOADW(12) LOADW(13) LOADW(14) LOADW(15)
#undef LOADW

    // ---- input weights: full-8 per lane; r/z pre-halved (half_sum doubles),
    //      n full-scale (no half_sum on the x part) ----
    float wxr0,wxr1,wxr2,wxr3,wxr4,wxr5,wxr6,wxr7;
    float wxz0,wxz1,wxz2,wxz3,wxz4,wxz5,wxz6,wxz7;
    float wxn0,wxn1,wxn2,wxn3,wxn4,wxn5,wxn6,wxn7;
#define LOADX(I)                                                                  \
    wxr##I = 0.5f * ALPHA * Wf[(0*Hn + j)*In + I];                                \
    wxz##I = 0.5f * ALPHA * Wf[(1*Hn + j)*In + I];                                \
    wxn##I = BETA         * Wf[(2*Hn + j)*In + I];                                \
    KEEP(wxr##I); KEEP(wxz##I); KEEP(wxn##I);
    LOADX(0) LOADX(1) LOADX(2) LOADX(3) LOADX(4) LOADX(5) LOADX(6) LOADX(7)
#undef LOADX

    // biases: r/z and n-h halved (pass through half_sum); n-x full
    float br_h  = 0.5f * ALPHA * (b_ih[j]        + b_hh[j]);
    float bz_h  = 0.5f * ALPHA * (b_ih[Hn + j]   + b_hh[Hn + j]);
    float bxn_f = BETA * b_ih[2*Hn + j];
    float bhn_h = 0.5f * BETA * b_hh[2*Hn + j];
    KEEP(br_h); KEEP(bz_h); KEEP(bxn_f); KEEP(bhn_h);

    const float* xb   = x + (size_t)b * Tn * In;
    float* latb_u     = latents + (size_t)b * Tn * Hn;   // uniform base
    const float* refp = xb + 4 * In;                     // next refill = x[4]

    float hj = 0.f;
    float H0=0.f,H1=0.f,H2=0.f,H3=0.f,H4=0.f,H5=0.f,H6=0.f,H7=0.f,
          H8=0.f,H9=0.f,H10=0.f,H11=0.f,H12=0.f,H13=0.f,H14=0.f,H15=0.f;

    // ---- 4-deep x ring, uniform addresses (8 floats/step) ----
    float4 a0 = *(const float4*)&xb[0*In], b0 = *(const float4*)&xb[0*In + 4];
    float4 a1 = *(const float4*)&xb[1*In], b1 = *(const float4*)&xb[1*In + 4];
    float4 a2 = *(const float4*)&xb[2*In], b2 = *(const float4*)&xb[2*In + 4];
    float4 a3 = *(const float4*)&xb[3*In], b3 = *(const float4*)&xb[3*In + 4];

    // main loop: steps 0..4091 (1023 groups of 4), refilling x[s+4]
#pragma unroll 1
    for (int s0 = 0; s0 < Tn - 4; s0 += 4) {
        GRU_STEP(a0, b0, a0, b0, true)
        GRU_STEP(a1, b1, a1, b1, true)
        GRU_STEP(a2, b2, a2, b2, true)
        GRU_STEP(a3, b3, a3, b3, true)
    }
    // epilogue: steps 4092..4095 (slots hold x[4092..4095]); no refills
    GRU_STEP(a0, b0, a0, b0, false)
    GRU_STEP(a1, b1, a1, b1, false)
    GRU_STEP(a2, b2, a2, b2, false)
    GRU_STEP(a3, b3, a3, b3, false)
}
#undef KEEP

// outputs[b,t,o] = sum_h latents[b,t,h] * E[h,o]
__global__ void decode_kernel(const float* __restrict__ lat,
                              const float* __restrict__ E,
                              float* __restrict__ out) {
    __shared__ float ldsE[Hn * TGTn];
    int tid = threadIdx.x;
    if (tid < Hn * TGTn) ldsE[tid] = E[tid];
    __syncthreads();
    size_t idx = (size_t)blockIdx.x * 256 + tid;   // over B*T*8
    int o      = (int)(idx & (TGTn - 1));
    size_t row = idx >> 3;
    const float* lrow = lat + row * Hn;
    float acc = 0.f;
#pragma unroll
    for (int h = 0; h < Hn; ++h)
        acc = fmaf(lrow[h], ldsE[h * TGTn + o], acc);
    out[idx] = acc;
}

extern "C" void kernel_launch(void* const* d_in, const int* in_sizes, int n_in,
                              void* d_out, int out_size, void* d_ws, size_t ws_size,
                              hipStream_t stream) {
    const float* x    = (const float*)d_in[0];
    const float* E    = (const float*)d_in[1];
    const float* w_ih = (const float*)d_in[2];
    const float* w_hh = (const float*)d_in[3];
    const float* b_ih = (const float*)d_in[4];
    const float* b_hh = (const float*)d_in[5];

    float* out = (float*)d_out;                          // [B,T,8]
    float* lat = out + (size_t)Bsz * Tn * TGTn;          // [B,T,32]
    float* Wf  = (float*)d_ws;                           // [96,8]

    fuse_wih_kernel<<<1, 768, 0, stream>>>(w_ih, E, Wf);
    gru_kernel<<<Bsz, 64, 0, stream>>>(x, Wf, w_hh, b_ih, b_hh, lat);
    decode_kernel<<<(Bsz * Tn * TGTn) / 256, 256, 0, stream>>>(lat, E, out);
}